// Round 2
// baseline (496.741 us; speedup 1.0000x reference)
//
#include <hip/hip_runtime.h>

#define NB 2
#define NC 20
#define CELL_F 30      // floats per cell: 2*5 + 20
#define TILE 64        // cells per (single-wave) block tile
#define TILE_F4 480    // float4 per tensor per tile (64*30/4)
#define LDS_F4 960     // both tensors

// ---------------- init: zero the accumulators in workspace ----------------
__global__ void init_ws_kernel(double* ws) {
    int i = threadIdx.x;
    if (i < 8) ws[i] = 0.0;
}

// IoU exactly mirroring the reference arithmetic (clip-at-0, eps=1e-6)
__device__ __forceinline__ float iou_ref(const float* a, const float* b) {
    float ax1 = a[0] - a[2] * 0.5f, ay1 = a[1] - a[3] * 0.5f;
    float ax2 = a[0] + a[2] * 0.5f, ay2 = a[1] + a[3] * 0.5f;
    float bx1 = b[0] - b[2] * 0.5f, by1 = b[1] - b[3] * 0.5f;
    float bx2 = b[0] + b[2] * 0.5f, by2 = b[1] + b[3] * 0.5f;
    float iw = fmaxf(fminf(ax2, bx2) - fmaxf(ax1, bx1), 0.0f);
    float ih = fmaxf(fminf(ay2, by2) - fmaxf(ay1, by1), 0.0f);
    float inter = iw * ih;
    float area_a = fmaxf(ax2 - ax1, 0.0f) * fmaxf(ay2 - ay1, 0.0f);
    float area_b = fmaxf(bx2 - bx1, 0.0f) * fmaxf(by2 - by1, 0.0f);
    return inter / (area_a + area_b - inter + 1e-6f);
}

// ---------------- main reduction kernel ----------------
// One wave per block. Stage a 64-cell tile into LDS with linear (fully
// coalesced) global_load_lds width-16 ops, then each lane processes one cell.
// ws[0]=box_sse, ws[1]=obj_sse, ws[2]=noobj_sse, ws[3]=cls_sse, ws[4]=n_obj
__global__ __launch_bounds__(64) void yolo_loss_kernel(
    const float* __restrict__ gt, const float* __restrict__ pred,
    long long ncells, double* __restrict__ ws) {
    __shared__ float4 lds4[LDS_F4];   // [0,480): gt tile, [480,960): pred tile

    const int lane = threadIdx.x;     // 0..63
    const float4* gt4 = (const float4*)gt;
    const float4* pr4 = (const float4*)pred;

    long long ntiles = (ncells + TILE - 1) / TILE;
    long long maxF4  = (ncells * (long long)CELL_F) >> 2;  // per-tensor f4 count

    float box_s = 0.f, obj_s = 0.f, noobj_s = 0.f, cls_s = 0.f, cnt_s = 0.f;

    for (long long t = blockIdx.x; t < ntiles; t += gridDim.x) {
        long long base = t * (long long)TILE_F4;

        // ---- stage: 15 iterations x 64 lanes x 16B = 15,360 B, linear ----
        #pragma unroll
        for (int j = 0; j < 15; ++j) {
            int s = j * 64 + lane;                       // 0..959 (LDS f4 slot)
            bool isGt = (s < TILE_F4);
            long long g = base + (isGt ? s : s - TILE_F4);
            if (g >= maxF4) g = maxF4 - 1;               // tail safety clamp
            const float4* src = isGt ? (gt4 + g) : (pr4 + g);
            __builtin_amdgcn_global_load_lds(
                (const __attribute__((address_space(1))) void*)src,
                (__attribute__((address_space(3))) void*)(lds4 + s),
                16, 0, 0);
        }
        __syncthreads();   // drains vmcnt(0): staged data visible in LDS

        long long c = t * (long long)TILE + lane;
        if (c < ncells) {
            // lane's cell: gt floats at LDS [lane*30, +30), pred at +1920
            const float2* l2 = (const float2*)lds4;
            float2 gbuf[15], pbuf[15];
            #pragma unroll
            for (int j = 0; j < 15; ++j) gbuf[j] = l2[lane * 15 + j];
            #pragma unroll
            for (int j = 0; j < 15; ++j) pbuf[j] = l2[960 + lane * 15 + j];
            const float* gf = (const float*)gbuf;
            const float* pf = (const float*)pbuf;

            // layout: [0..3]=box0, [4]=conf0, [5..8]=box1, [9]=conf1, [10..29]=cls
            float iou0 = iou_ref(gf + 0, pf + 0);
            float iou1 = iou_ref(gf + 5, pf + 5);
            int   idx  = (iou1 > iou0) ? 1 : 0;   // argmax, ties -> 0
            float miou = fmaxf(iou0, iou1);

            bool  obj = (gf[4] == 1.0f);
            float m   = obj ? 1.0f : 0.0f;

            float sse0 = 0.f, sse1 = 0.f;
            #pragma unroll
            for (int j = 0; j < 4; ++j) {
                float d0 = pf[j] - gf[j];         sse0 += d0 * d0;
                float d1 = pf[5 + j] - gf[5 + j]; sse1 += d1 * d1;
            }
            box_s += m * (idx ? sse1 : sse0);

            float pc0 = pf[4], pc1 = pf[9];
            float pcr = idx ? pc1 : pc0;   // responsible box conf
            float pco = idx ? pc0 : pc1;   // other box conf
            float dr  = pcr - miou;
            obj_s   += m * dr * dr;
            noobj_s += obj ? (pco * pco) : (pc0 * pc0 + pc1 * pc1);

            float cs = 0.f;
            #pragma unroll
            for (int j = 10; j < 30; ++j) {
                float d = pf[j] - gf[j];
                cs += d * d;
            }
            cls_s += m * cs;
            cnt_s += m;
        }
        __syncthreads();   // reads complete before next tile's staging overwrites
    }

    // single-wave block: 64-lane shuffle reduce, lane 0 atomics
    #pragma unroll
    for (int off = 32; off > 0; off >>= 1) {
        box_s   += __shfl_down(box_s, off);
        obj_s   += __shfl_down(obj_s, off);
        noobj_s += __shfl_down(noobj_s, off);
        cls_s   += __shfl_down(cls_s, off);
        cnt_s   += __shfl_down(cnt_s, off);
    }
    if (lane == 0) {
        atomicAdd(&ws[0], (double)box_s);
        atomicAdd(&ws[1], (double)obj_s);
        atomicAdd(&ws[2], (double)noobj_s);
        atomicAdd(&ws[3], (double)cls_s);
        atomicAdd(&ws[4], (double)cnt_s);
    }
}

// ---------------- finalize: compute the 3 outputs ----------------
__global__ void finalize_kernel(const double* __restrict__ ws,
                                float* __restrict__ out, double ncells) {
    if (threadIdx.x == 0 && blockIdx.x == 0) {
        double cnt   = ws[4];
        double nobj  = fmax(cnt, 1.0);
        double nno   = fmax(2.0 * ncells - cnt, 1.0);  // n_noobj = 2*cells - n_obj
        double box   = ws[0], objl = ws[1], noobj = ws[2], cls = ws[3];
        out[0] = (float)(5.0 * box / (nobj * 4.0));          // LAMBDA_COORD * box_loss
        out[1] = (float)(0.5 * noobj / nno + objl / nobj);   // LAMBDA_NOOBJ*noobj + obj
        out[2] = (float)(cls / (nobj * 20.0));               // cls_loss
    }
}

extern "C" void kernel_launch(void* const* d_in, const int* in_sizes, int n_in,
                              void* d_out, int out_size, void* d_ws, size_t ws_size,
                              hipStream_t stream) {
    const float* gt   = (const float*)d_in[0];
    const float* pred = (const float*)d_in[1];
    float* out = (float*)d_out;
    double* ws = (double*)d_ws;

    long long ncells = (long long)in_sizes[0] / CELL_F;
    long long ntiles = (ncells + TILE - 1) / TILE;

    init_ws_kernel<<<1, 64, 0, stream>>>(ws);

    // 10 blocks/CU (LDS-limited: 15,360 B each) x 256 CU = 2560 resident
    long long blocks = 2560;
    if (ntiles < blocks) blocks = ntiles;
    yolo_loss_kernel<<<(int)blocks, 64, 0, stream>>>(gt, pred, ncells, ws);

    finalize_kernel<<<1, 64, 0, stream>>>(ws, out, (double)ncells);
}

// Round 3
// 435.250 us; speedup vs baseline: 1.1413x; 1.1413x over previous
//
#include <hip/hip_runtime.h>

#define CELL_F 30      // floats per cell: 2*5 + 20
#define TILE 64        // cells per tile (per single-wave block)
#define HALF 480       // float4 slots per tensor per tile (64*30/4)
#define SLOTS 960      // float4 slots per buffer (both tensors)

// ---------------- init: zero the accumulators in workspace ----------------
__global__ void init_ws_kernel(double* ws) {
    int i = threadIdx.x;
    if (i < 8) ws[i] = 0.0;
}

// IoU exactly mirroring the reference arithmetic (clip-at-0, eps=1e-6)
__device__ __forceinline__ float iou_ref(const float* a, const float* b) {
    float ax1 = a[0] - a[2] * 0.5f, ay1 = a[1] - a[3] * 0.5f;
    float ax2 = a[0] + a[2] * 0.5f, ay2 = a[1] + a[3] * 0.5f;
    float bx1 = b[0] - b[2] * 0.5f, by1 = b[1] - b[3] * 0.5f;
    float bx2 = b[0] + b[2] * 0.5f, by2 = b[1] + b[3] * 0.5f;
    float iw = fmaxf(fminf(ax2, bx2) - fmaxf(ax1, bx1), 0.0f);
    float ih = fmaxf(fminf(ay2, by2) - fmaxf(ay1, by1), 0.0f);
    float inter = iw * ih;
    float area_a = fmaxf(ax2 - ax1, 0.0f) * fmaxf(ay2 - ay1, 0.0f);
    float area_b = fmaxf(bx2 - bx1, 0.0f) * fmaxf(by2 - by1, 0.0f);
    return inter / (area_a + area_b - inter + 1e-6f);
}

// ---------------- main reduction kernel ----------------
// One wave per block, double-buffered LDS, counted-vmcnt pipeline (no barriers).
// Invariant: every STAGE issues exactly 15 global_load_lds; every iteration
// waits vmcnt(15) so the freshly-issued next-tile loads stay in flight.
// ws[0]=box_sse, ws[1]=obj_sse, ws[2]=noobj_sse, ws[3]=cls_sse, ws[4]=n_obj
__global__ __launch_bounds__(64) void yolo_loss_kernel(
    const float* __restrict__ gt, const float* __restrict__ pred,
    long long ncells, double* __restrict__ ws) {
    __shared__ float4 lds4[2][SLOTS];

    const int lane = threadIdx.x;     // 0..63
    const float4* gt4 = (const float4*)gt;
    const float4* pr4 = (const float4*)pred;

    const long long ntiles = (ncells + TILE - 1) / TILE;
    const long long maxF4  = (ncells * (long long)CELL_F) >> 2;  // per-tensor f4 count
    const long long G      = gridDim.x;

    float box_s = 0.f, obj_s = 0.f, noobj_s = 0.f, cls_s = 0.f, cnt_s = 0.f;

    // STAGE(buf, tile): 15 fully-linear global_load_lds dwordx4 (1 KiB each)
#define STAGE(BUF, T)                                                          \
    do {                                                                       \
        long long _base = (T) * (long long)HALF;                               \
        _Pragma("unroll")                                                      \
        for (int j = 0; j < 15; ++j) {                                         \
            int s = j * 64 + lane;                                             \
            bool isGt = (s < HALF);                                            \
            long long g = _base + (isGt ? s : s - HALF);                       \
            if (g >= maxF4) g = maxF4 - 1;                                     \
            const float4* src = isGt ? (gt4 + g) : (pr4 + g);                  \
            __builtin_amdgcn_global_load_lds(                                  \
                (const __attribute__((address_space(1))) void*)src,            \
                (__attribute__((address_space(3))) void*)&lds4[(BUF)][s],      \
                16, 0, 0);                                                     \
        }                                                                      \
    } while (0)

    long long t0 = blockIdx.x;
    int cur = 0;
    STAGE(0, t0);                               // prologue: 15 outstanding

    for (long long t = t0; t < ntiles; t += G) {
        long long tn = t + G;
        // prior ds_reads of buf cur^1 fully retired before we overwrite it
        asm volatile("s_waitcnt lgkmcnt(0)" ::: "memory");
        __builtin_amdgcn_sched_barrier(0);
        STAGE(cur ^ 1, (tn < ntiles) ? tn : t); // dummy re-stage keeps 15-load cadence
        // wait only the OLDEST 15 (current buf); next tile's 15 stay in flight
        asm volatile("s_waitcnt vmcnt(15)" ::: "memory");
        __builtin_amdgcn_sched_barrier(0);

        long long c = t * (long long)TILE + lane;
        if (c < ncells) {
            const float2* l2 = (const float2*)lds4[cur];
            float2 gbuf[15], pbuf[15];
            #pragma unroll
            for (int j = 0; j < 15; ++j) gbuf[j] = l2[lane * 15 + j];
            #pragma unroll
            for (int j = 0; j < 15; ++j) pbuf[j] = l2[960 + lane * 15 + j];
            const float* gf = (const float*)gbuf;
            const float* pf = (const float*)pbuf;

            // layout: [0..3]=box0, [4]=conf0, [5..8]=box1, [9]=conf1, [10..29]=cls
            float iou0 = iou_ref(gf + 0, pf + 0);
            float iou1 = iou_ref(gf + 5, pf + 5);
            int   idx  = (iou1 > iou0) ? 1 : 0;   // argmax, ties -> 0
            float miou = fmaxf(iou0, iou1);

            bool  obj = (gf[4] == 1.0f);
            float m   = obj ? 1.0f : 0.0f;

            float sse0 = 0.f, sse1 = 0.f;
            #pragma unroll
            for (int j = 0; j < 4; ++j) {
                float d0 = pf[j] - gf[j];         sse0 += d0 * d0;
                float d1 = pf[5 + j] - gf[5 + j]; sse1 += d1 * d1;
            }
            box_s += m * (idx ? sse1 : sse0);

            float pc0 = pf[4], pc1 = pf[9];
            float pcr = idx ? pc1 : pc0;   // responsible box conf
            float pco = idx ? pc0 : pc1;   // other box conf
            float dr  = pcr - miou;
            obj_s   += m * dr * dr;
            noobj_s += obj ? (pco * pco) : (pc0 * pc0 + pc1 * pc1);

            float cs = 0.f;
            #pragma unroll
            for (int j = 10; j < 30; ++j) {
                float d = pf[j] - gf[j];
                cs += d * d;
            }
            cls_s += m * cs;
            cnt_s += m;
        }
        cur ^= 1;
    }
#undef STAGE

    // single-wave block: 64-lane shuffle reduce, lane 0 atomics
    #pragma unroll
    for (int off = 32; off > 0; off >>= 1) {
        box_s   += __shfl_down(box_s, off);
        obj_s   += __shfl_down(obj_s, off);
        noobj_s += __shfl_down(noobj_s, off);
        cls_s   += __shfl_down(cls_s, off);
        cnt_s   += __shfl_down(cnt_s, off);
    }
    if (lane == 0) {
        atomicAdd(&ws[0], (double)box_s);
        atomicAdd(&ws[1], (double)obj_s);
        atomicAdd(&ws[2], (double)noobj_s);
        atomicAdd(&ws[3], (double)cls_s);
        atomicAdd(&ws[4], (double)cnt_s);
    }
}

// ---------------- finalize: compute the 3 outputs ----------------
__global__ void finalize_kernel(const double* __restrict__ ws,
                                float* __restrict__ out, double ncells) {
    if (threadIdx.x == 0 && blockIdx.x == 0) {
        double cnt   = ws[4];
        double nobj  = fmax(cnt, 1.0);
        double nno   = fmax(2.0 * ncells - cnt, 1.0);  // n_noobj = 2*cells - n_obj
        double box   = ws[0], objl = ws[1], noobj = ws[2], cls = ws[3];
        out[0] = (float)(5.0 * box / (nobj * 4.0));          // LAMBDA_COORD * box_loss
        out[1] = (float)(0.5 * noobj / nno + objl / nobj);   // LAMBDA_NOOBJ*noobj + obj
        out[2] = (float)(cls / (nobj * 20.0));               // cls_loss
    }
}

extern "C" void kernel_launch(void* const* d_in, const int* in_sizes, int n_in,
                              void* d_out, int out_size, void* d_ws, size_t ws_size,
                              hipStream_t stream) {
    const float* gt   = (const float*)d_in[0];
    const float* pred = (const float*)d_in[1];
    float* out = (float*)d_out;
    double* ws = (double*)d_ws;

    long long ncells = (long long)in_sizes[0] / CELL_F;
    long long ntiles = (ncells + TILE - 1) / TILE;

    init_ws_kernel<<<1, 64, 0, stream>>>(ws);

    // LDS 30,720 B/block -> 5 blocks/CU x 256 CU = 1280 resident single-wave blocks
    long long blocks = 1280;
    if (ntiles < blocks) blocks = ntiles;
    yolo_loss_kernel<<<(int)blocks, 64, 0, stream>>>(gt, pred, ncells, ws);

    finalize_kernel<<<1, 64, 0, stream>>>(ws, out, (double)ncells);
}